// Round 16
// baseline (79.256 us; speedup 1.0000x reference)
//
#include <hip/hip_runtime.h>
#include <math.h>

#define IN_F  256
#define OUT_F 256
#define OTILE 64       // o per block; lane = o
#define BTILE 8        // b per block; 2 per wave
#define NTH   256
#define PSTRIDE 264    // fp16 per LDS row: 256 + 4-hp pad -> 528B, 16B-aligned, spreads banks

typedef _Float16 h2 __attribute__((ext_vector_type(2)));   // -> v_pk_* f16 ops

// out[b,o] = (1 + min_i t)*n0 + (max_i u - 1)*n1,  t=(x-1)*pe=pk_fma(x,pe,-pe), u=pk_fma(2,pe,t)
// pe = sigmoid(w0-w1) computed during staging (redundant across b-tiles; TRANS-pipe, overlapped).
// Load split: pe via LDS ds_read_b128 (32/wave), x via SMEM s_load (uniform) -> two pipes in parallel.
__global__ __launch_bounds__(NTH, 4)
void den_kernel(const float* __restrict__ x,
                const float* __restrict__ pew,
                const float* __restrict__ pnw,
                float* __restrict__ out)
{
    __shared__ __align__(16) _Float16 pe_lds[OTILE * PSTRIDE];   // ~33KB -> 4 blocks/CU

    const int tid = threadIdx.x;
    const int b0  = blockIdx.x * BTILE;
    const int o0  = blockIdx.y * OTILE;

    // ---- stage pe: 64 rows x 256 i fp16, padded rows; 2x b128 write per (thread,row) ----
    {
        const int r16 = tid >> 4;            // 0..15
        const int c   = tid & 15;            // 0..15: lane covers i in [c*16, c*16+16)
        #pragma unroll
        for (int rg = 0; rg < 4; ++rg) {
            const int o = rg * 16 + r16;     // 0..63
            const float4* wp = reinterpret_cast<const float4*>(pew + (size_t)(o0 + o) * (IN_F * 2)) + c * 8;
            h2 v[8];
            #pragma unroll
            for (int k = 0; k < 8; ++k) {    // 8 float4 = 16 (w0,w1) pairs = 16 pe values
                float4 w = wp[k];
                float pe0 = __builtin_amdgcn_rcpf(1.0f + __expf(w.y - w.x));
                float pe1 = __builtin_amdgcn_rcpf(1.0f + __expf(w.w - w.z));
                v[k].x = (_Float16)pe0; v[k].y = (_Float16)pe1;
            }
            _Float16* dst = &pe_lds[o * PSTRIDE + c * 16];
            reinterpret_cast<h2*>(dst)[0] = v[0];  reinterpret_cast<h2*>(dst)[1] = v[1];
            reinterpret_cast<h2*>(dst)[2] = v[2];  reinterpret_cast<h2*>(dst)[3] = v[3];
            reinterpret_cast<h2*>(dst)[4] = v[4];  reinterpret_cast<h2*>(dst)[5] = v[5];
            reinterpret_cast<h2*>(dst)[6] = v[6];  reinterpret_cast<h2*>(dst)[7] = v[7];
        }
    }
    __syncthreads();   // the only barrier

    const int lane = tid & 63;                                  // lane = o offset
    const int wid  = __builtin_amdgcn_readfirstlane(tid >> 6);  // SGPR -> uniform x addrs
    const int bb0  = b0 + wid * 2;                              // 2 b-rows per wave
    const _Float16* rowp = &pe_lds[lane * PSTRIDE];

    const h2 two2 = {(_Float16)2.0f, (_Float16)2.0f};
    h2 mn[2], mx[2];
    #pragma unroll
    for (int j = 0; j < 2; ++j) {
        mn[j].x = mn[j].y = (_Float16)INFINITY;
        mx[j].x = mx[j].y = (_Float16)(-INFINITY);
    }

    const float4* xr0 = reinterpret_cast<const float4*>(x + (size_t)(bb0 + 0) * IN_F);  // uniform
    const float4* xr1 = reinterpret_cast<const float4*>(x + (size_t)(bb0 + 1) * IN_F);  // uniform

    // ---- main loop: 32 chunks of 8 i: 1 ds_read_b128 (pe) + 4 uniform float4 (x, SMEM) ----
    #pragma unroll 8
    for (int c = 0; c < 32; ++c) {
        // pe[i..i+7] for this lane's o
        h2 p[4];
        *reinterpret_cast<float4*>(p) = *reinterpret_cast<const float4*>(rowp + c * 8);

        #pragma unroll
        for (int j = 0; j < 2; ++j) {
            const float4* xr = j ? xr1 : xr0;
            float4 xa = xr[c * 2 + 0];       // i .. i+3   (s_load path)
            float4 xb = xr[c * 2 + 1];       // i+4 .. i+7
            h2 xh[4];
            xh[0] = __builtin_bit_cast(h2, __builtin_amdgcn_cvt_pkrtz(xa.x, xa.y));
            xh[1] = __builtin_bit_cast(h2, __builtin_amdgcn_cvt_pkrtz(xa.z, xa.w));
            xh[2] = __builtin_bit_cast(h2, __builtin_amdgcn_cvt_pkrtz(xb.x, xb.y));
            xh[3] = __builtin_bit_cast(h2, __builtin_amdgcn_cvt_pkrtz(xb.z, xb.w));
            h2 t0 = __builtin_elementwise_fma(xh[0], p[0], -p[0]);
            h2 t1 = __builtin_elementwise_fma(xh[1], p[1], -p[1]);
            h2 t2 = __builtin_elementwise_fma(xh[2], p[2], -p[2]);
            h2 t3 = __builtin_elementwise_fma(xh[3], p[3], -p[3]);
            h2 u0 = __builtin_elementwise_fma(two2, p[0], t0);
            h2 u1 = __builtin_elementwise_fma(two2, p[1], t1);
            h2 u2 = __builtin_elementwise_fma(two2, p[2], t2);
            h2 u3 = __builtin_elementwise_fma(two2, p[3], t3);
            mn[j] = __builtin_elementwise_min(mn[j],
                      __builtin_elementwise_min(__builtin_elementwise_min(t0, t1),
                                                __builtin_elementwise_min(t2, t3)));
            mx[j] = __builtin_elementwise_max(mx[j],
                      __builtin_elementwise_max(__builtin_elementwise_max(u0, u1),
                                                __builtin_elementwise_max(u2, u3)));
        }
    }

    // ---- epilogue: node softmax + combine; coalesced b32 stores ----
    const int o = o0 + lane;
    float2 nw = *reinterpret_cast<const float2*>(pnw + 2 * (size_t)o);
    float n0 = __builtin_amdgcn_rcpf(1.0f + __expf(nw.y - nw.x));
    float n1 = 1.0f - n0;
    #pragma unroll
    for (int j = 0; j < 2; ++j) {
        float mnf = fminf((float)mn[j].x, (float)mn[j].y);
        float mxf = fmaxf((float)mx[j].x, (float)mx[j].y);
        out[(size_t)(bb0 + j) * OUT_F + o] = (mnf + 1.0f) * n0 + (mxf - 1.0f) * n1;
    }
}

extern "C" void kernel_launch(void* const* d_in, const int* in_sizes, int n_in,
                              void* d_out, int out_size, void* d_ws, size_t ws_size,
                              hipStream_t stream) {
    (void)d_ws; (void)ws_size; (void)n_in; (void)out_size;
    const float* x   = (const float*)d_in[0];
    const float* pew = (const float*)d_in[1];
    const float* pnw = (const float*)d_in[2];
    float* out = (float*)d_out;
    const int B = in_sizes[0] / IN_F;          // 2048
    dim3 grid(B / BTILE, OUT_F / OTILE);       // 256 x 4 = 1024 blocks (4/CU)
    den_kernel<<<grid, NTH, 0, stream>>>(x, pew, pnw, out);
}

// Round 17
// 70.497 us; speedup vs baseline: 1.1243x; 1.1243x over previous
//
#include <hip/hip_runtime.h>
#include <math.h>

#define IN_F  256
#define OUT_F 256
#define OTILE 64       // o per block; lane = o
#define BTILE 8        // b per block; 2 per wave
#define NTH   256

typedef _Float16 h2 __attribute__((ext_vector_type(2)));   // -> v_pk_* f16 ops
union u4h { uint4 u; h2 h[4]; };                           // 16B = 8 fp16

// ---------------- prep ----------------
// A: pe16blk[c][o][8] fp16, c=i/8 (32*256*16B = 128KB): sigmoid computed ONCE total.
//    Main reads it lane=o coalesced (16B/lane, consecutive lanes 16B apart).
// B: x16[b][c] uint4 = 8 fp16 (2048*32*16B = 1MB): main reads via uniform s_load.
__global__ __launch_bounds__(256)
void prep_kernel(const float* __restrict__ x,
                 const float* __restrict__ pew,
                 uint4* __restrict__ pe16,
                 uint4* __restrict__ x16)
{
    const int bid = blockIdx.x;
    const int t   = threadIdx.x;
    if (bid < 32) {                          // pe: thread = o, block = i-chunk c
        const int c = bid;
        const int o = t;
        const float4* wp = reinterpret_cast<const float4*>(pew) + (size_t)o * 128 + c * 4;
        u4h r;
        #pragma unroll
        for (int q = 0; q < 4; ++q) {        // 4 float4 = 8 (w0,w1) pairs = 8 pe
            float4 w = wp[q];
            float pe0 = __builtin_amdgcn_rcpf(1.0f + __expf(w.y - w.x));
            float pe1 = __builtin_amdgcn_rcpf(1.0f + __expf(w.w - w.z));
            r.h[q].x = (_Float16)pe0; r.h[q].y = (_Float16)pe1;
        }
        pe16[c * 256 + o] = r.u;
    } else {                                 // x: 65536 uint4
        const int u = (bid - 32) * 256 + t;
        const float4* xp = reinterpret_cast<const float4*>(x) + (size_t)u * 2;
        float4 a = xp[0], b = xp[1];
        u4h r;
        r.h[0] = __builtin_bit_cast(h2, __builtin_amdgcn_cvt_pkrtz(a.x, a.y));
        r.h[1] = __builtin_bit_cast(h2, __builtin_amdgcn_cvt_pkrtz(a.z, a.w));
        r.h[2] = __builtin_bit_cast(h2, __builtin_amdgcn_cvt_pkrtz(b.x, b.y));
        r.h[3] = __builtin_bit_cast(h2, __builtin_amdgcn_cvt_pkrtz(b.z, b.w));
        x16[u] = r.u;
    }
}

// ---------------- main: NO LDS, NO barrier ----------------
// out[b,o] = (1 + min_i t)*n0 + (max_i u - 1)*n1; t = pk_fma(x,pe,-pe); u = pk_fma(2,pe,t).
// Per 8-i chunk: 1 coalesced VMEM (pe) + 2 uniform SMEM (x) + 32 pk-fp16 VALU.
__global__ __launch_bounds__(NTH, 4)
void den_main(const uint4* __restrict__ pe16,
              const uint4* __restrict__ x16,
              const float* __restrict__ pnw,
              float* __restrict__ out)
{
    const int tid  = threadIdx.x;
    const int lane = tid & 63;                                  // lane = o offset
    const int wid  = __builtin_amdgcn_readfirstlane(tid >> 6);  // SGPR -> uniform x addrs
    const int b0   = blockIdx.x * BTILE;
    const int o0   = blockIdx.y * OTILE;
    const int bb0  = b0 + wid * 2;                              // 2 b-rows per wave

    const uint4* per = pe16 + o0 + lane;                        // + c*256 per chunk
    const uint4* xr0 = x16 + (size_t)(bb0 + 0) * 32;            // uniform (s_load path)
    const uint4* xr1 = x16 + (size_t)(bb0 + 1) * 32;

    const h2 two2 = {(_Float16)2.0f, (_Float16)2.0f};
    h2 mn[2], mx[2];
    #pragma unroll
    for (int j = 0; j < 2; ++j) {
        mn[j].x = mn[j].y = (_Float16)INFINITY;
        mx[j].x = mx[j].y = (_Float16)(-INFINITY);
    }

    #pragma unroll 4
    for (int c = 0; c < 32; ++c) {
        u4h p;  p.u  = per[c * 256];     // pe[i..i+7] for this lane's o (coalesced)
        u4h xa; xa.u = xr0[c];           // x row bb0,   i..i+7 (uniform)
        u4h xb; xb.u = xr1[c];           // x row bb0+1, i..i+7 (uniform)

        { // j = 0
            h2 t0 = __builtin_elementwise_fma(xa.h[0], p.h[0], -p.h[0]);
            h2 t1 = __builtin_elementwise_fma(xa.h[1], p.h[1], -p.h[1]);
            h2 t2 = __builtin_elementwise_fma(xa.h[2], p.h[2], -p.h[2]);
            h2 t3 = __builtin_elementwise_fma(xa.h[3], p.h[3], -p.h[3]);
            h2 u0 = __builtin_elementwise_fma(two2, p.h[0], t0);
            h2 u1 = __builtin_elementwise_fma(two2, p.h[1], t1);
            h2 u2 = __builtin_elementwise_fma(two2, p.h[2], t2);
            h2 u3 = __builtin_elementwise_fma(two2, p.h[3], t3);
            mn[0] = __builtin_elementwise_min(mn[0],
                      __builtin_elementwise_min(__builtin_elementwise_min(t0, t1),
                                                __builtin_elementwise_min(t2, t3)));
            mx[0] = __builtin_elementwise_max(mx[0],
                      __builtin_elementwise_max(__builtin_elementwise_max(u0, u1),
                                                __builtin_elementwise_max(u2, u3)));
        }
        { // j = 1
            h2 t0 = __builtin_elementwise_fma(xb.h[0], p.h[0], -p.h[0]);
            h2 t1 = __builtin_elementwise_fma(xb.h[1], p.h[1], -p.h[1]);
            h2 t2 = __builtin_elementwise_fma(xb.h[2], p.h[2], -p.h[2]);
            h2 t3 = __builtin_elementwise_fma(xb.h[3], p.h[3], -p.h[3]);
            h2 u0 = __builtin_elementwise_fma(two2, p.h[0], t0);
            h2 u1 = __builtin_elementwise_fma(two2, p.h[1], t1);
            h2 u2 = __builtin_elementwise_fma(two2, p.h[2], t2);
            h2 u3 = __builtin_elementwise_fma(two2, p.h[3], t3);
            mn[1] = __builtin_elementwise_min(mn[1],
                      __builtin_elementwise_min(__builtin_elementwise_min(t0, t1),
                                                __builtin_elementwise_min(t2, t3)));
            mx[1] = __builtin_elementwise_max(mx[1],
                      __builtin_elementwise_max(__builtin_elementwise_max(u0, u1),
                                                __builtin_elementwise_max(u2, u3)));
        }
    }

    // ---- epilogue: node softmax + combine; coalesced b32 stores ----
    const int o = o0 + lane;
    float2 nw = *reinterpret_cast<const float2*>(pnw + 2 * (size_t)o);
    float n0 = __builtin_amdgcn_rcpf(1.0f + __expf(nw.y - nw.x));
    float n1 = 1.0f - n0;
    #pragma unroll
    for (int j = 0; j < 2; ++j) {
        float mnf = fminf((float)mn[j].x, (float)mn[j].y);
        float mxf = fmaxf((float)mx[j].x, (float)mx[j].y);
        out[(size_t)(bb0 + j) * OUT_F + o] = (mnf + 1.0f) * n0 + (mxf - 1.0f) * n1;
    }
}

extern "C" void kernel_launch(void* const* d_in, const int* in_sizes, int n_in,
                              void* d_out, int out_size, void* d_ws, size_t ws_size,
                              hipStream_t stream) {
    (void)ws_size; (void)n_in; (void)out_size;
    const float* x   = (const float*)d_in[0];
    const float* pew = (const float*)d_in[1];
    const float* pnw = (const float*)d_in[2];
    float* out = (float*)d_out;

    uint4* pe16 = (uint4*)d_ws;                          // 128KB blocked pe table
    uint4* x16  = (uint4*)((char*)d_ws + 131072);        // 1MB fp16 x

    prep_kernel<<<288, 256, 0, stream>>>(x, pew, pe16, x16);

    const int B = in_sizes[0] / IN_F;          // 2048
    dim3 grid(B / BTILE, OUT_F / OTILE);       // 256 x 4 = 1024 blocks (4/CU)
    den_main<<<grid, NTH, 0, stream>>>(pe16, x16, pnw, out);
}